// Round 2
// baseline (312.107 us; speedup 1.0000x reference)
//
#include <hip/hip_runtime.h>
#include <hip/hip_bf16.h>

// WindowAttention (Swin shifted-window) for MI355X.
// Inputs/outputs are float32 (per reference dtypes); compute via
// v_mfma_f32_16x16x32_bf16 with f32 accumulation (2% tolerance allows bf16).
//
// Fragment layout (gfx950, verified in learn_hip m89/m97):
//   A (16x32): lane l holds A[l&15][8*(l>>4)+j], j=0..7  (contiguous 8 in k)
//   B (32x16): lane l holds B[8*(l>>4)+j][l&15]
//   C/D      : lane l reg r -> C[4*(l>>4)+r][l&15]

typedef __bf16 bf16x8 __attribute__((ext_vector_type(8)));
typedef float f32x4 __attribute__((ext_vector_type(4)));
using bf = __bf16;

#define MFMA16(a, b, c) __builtin_amdgcn_mfma_f32_16x16x32_bf16((a), (b), (c), 0, 0, 0)

static constexpr float kNEG = -1000000000.0f;
static constexpr float kScale = 0.17677669529663687f;  // 32^-0.5

// workspace layout (bytes)
static constexpr size_t OFF_WQKVT = 0;                    // bf16 [576][192]
static constexpr size_t OFF_WOUTT = 221184;               // bf16 [192][192]
static constexpr size_t OFF_TBL   = 294912;               // f32  [4][64][64]
static constexpr size_t OFF_Q     = 360448;               // bf16 [12288][49][32]
static constexpr size_t OFF_K     = OFF_Q + 38535168ull;  // bf16 [12288][49][32]
static constexpr size_t OFF_V     = OFF_K + 38535168ull;  // bf16 [12288][32][64] (V^T, pad zeroed)
static constexpr size_t OFF_O2    = OFF_V + 50331648ull;  // bf16 [32][56][56][192]

__device__ __forceinline__ bf16x8 ld8(const bf* p) {
  return *reinterpret_cast<const bf16x8*>(p);
}

// load 8 contiguous f32, convert to bf16x8
__device__ __forceinline__ bf16x8 ldf8(const float* p) {
  bf16x8 v;
#pragma unroll
  for (int j = 0; j < 8; ++j) v[j] = (bf)p[j];
  return v;
}

__device__ __forceinline__ bf16x8 zero8() {
  bf16x8 v;
#pragma unroll
  for (int j = 0; j < 8; ++j) v[j] = (bf)0.0f;
  return v;
}

// ---------------- kernel 0: weight transposes + bias/mask tables ----------------
__global__ void prep_kernel(const float* __restrict__ wqkv, const float* __restrict__ wout,
                            const float* __restrict__ pos, char* __restrict__ ws) {
  bf* wqkvT = (bf*)(ws + OFF_WQKVT);
  bf* woutT = (bf*)(ws + OFF_WOUTT);
  float* tbl = (float*)(ws + OFF_TBL);
  int tid = blockIdx.x * blockDim.x + threadIdx.x;
  int nthr = gridDim.x * blockDim.x;
  for (int i = tid; i < 192 * 576; i += nthr) {
    int k = i / 576, n = i % 576;
    wqkvT[n * 192 + k] = (bf)wqkv[i];
  }
  for (int i = tid; i < 192 * 192; i += nthr) {
    int k = i / 192, n = i % 192;
    woutT[n * 192 + k] = (bf)wout[i];
  }
  for (int i = tid; i < 4 * 64 * 64; i += nthr) {
    int type = i >> 12, rem = i & 4095, r = rem >> 6, c = rem & 63;
    float v;
    if (r < 49 && c < 49) {
      int ix = r / 7, iy = r % 7, jx = c / 7, jy = c % 7;
      v = pos[(jx - ix + 6) * 13 + (jy - iy + 6)];
      if ((type & 1) && ((r >= 28) != (c >= 28))) v += kNEG;   // ul mask (last window-row)
      if ((type & 2) && ((iy >= 4) != (jy >= 4))) v += kNEG;   // lr mask (last window-col)
    } else {
      v = kNEG;  // pad cols -> P=0; pad rows discarded
    }
    tbl[i] = v;
  }
}

// ---------------- kernel 1: QKV projection (roll fused), window layout ----------------
// grid: 2048 blocks (b*64+win), 256 threads (4 waves). wave w: cols [w*144, w*144+144)
__global__ __launch_bounds__(256) void qkv_kernel(const float* __restrict__ x,
                                                  char* __restrict__ ws) {
  const bf* wqkvT = (const bf*)(ws + OFF_WQKVT);
  bf* Qb = (bf*)(ws + OFF_Q);
  bf* Kb = (bf*)(ws + OFF_K);
  bf* Vb = (bf*)(ws + OFF_V);

  int bw = blockIdx.x;
  int b = bw >> 6, win = bw & 63;
  int wh = win >> 3, wwi = win & 7;
  int wave = threadIdx.x >> 6, lane = threadIdx.x & 63;
  int l15 = lane & 15, g = lane >> 4;

  // per-lane A row pointers (roll fused); rows >= 49 produce zero frags
  const float* arow[4];
  bool mvalid[4];
#pragma unroll
  for (int mt = 0; mt < 4; ++mt) {
    int t = mt * 16 + l15;
    mvalid[mt] = (t < 49);
    int tcl = t > 48 ? 48 : t;
    int tr = tcl / 7, tc = tcl % 7;
    int h = wh * 7 + tr + 3; if (h >= 56) h -= 56;
    int w = wwi * 7 + tc + 3; if (w >= 56) w -= 56;
    arow[mt] = x + (((size_t)b * 56 + h) * 56 + w) * 192;
  }

  bf16x8 zf = zero8();
  f32x4 acc[4][9] = {};
  int nbase = wave * 144;
#pragma unroll
  for (int ks = 0; ks < 6; ++ks) {
    bf16x8 a[4];
#pragma unroll
    for (int mt = 0; mt < 4; ++mt) {
      a[mt] = ldf8(arow[mt] + ks * 32 + g * 8);
      if (!mvalid[mt]) a[mt] = zf;
    }
#pragma unroll
    for (int nt = 0; nt < 9; ++nt) {
      int n = nbase + nt * 16 + l15;
      bf16x8 bfr = ld8(wqkvT + (size_t)n * 192 + ks * 32 + g * 8);
#pragma unroll
      for (int mt = 0; mt < 4; ++mt) acc[mt][nt] = MFMA16(a[mt], bfr, acc[mt][nt]);
    }
  }

  // epilogue: scatter to Q / K / V^T buffers
#pragma unroll
  for (int nt = 0; nt < 9; ++nt) {
    int n = nbase + nt * 16 + l15;
    int s = n / 192;
    int hd = (n % 192) >> 5;
    int d = n & 31;
    size_t hb = (size_t)bw * 6 + hd;
#pragma unroll
    for (int mt = 0; mt < 4; ++mt) {
#pragma unroll
      for (int r = 0; r < 4; ++r) {
        int t = mt * 16 + g * 4 + r;
        bf bv = (bf)acc[mt][nt][r];
        if (s == 0) {
          if (t < 49) Qb[(hb * 49 + t) * 32 + d] = bv;
        } else if (s == 1) {
          if (t < 49) Kb[(hb * 49 + t) * 32 + d] = bv;
        } else {
          Vb[(hb * 32 + d) * 64 + t] = bv;  // rows t>=49 are exact zeros (padded A)
        }
      }
    }
  }
}

// ---------------- kernel 2: window attention, 1 wave per (window, head) ----------------
// grid: 12288 blocks, 64 threads
__global__ __launch_bounds__(64) void attn_kernel(char* __restrict__ ws) {
  __shared__ __align__(16) bf P[64 * 72];  // stride 72 elems: conflict-free b128 reads

  int id = blockIdx.x;              // bw*6 + head
  int bw = id / 6, head = id - bw * 6;
  int b = bw >> 6, win = bw & 63;
  int wh = win >> 3, wwi = win & 7;
  int type = ((wh == 7) ? 1 : 0) | ((wwi == 7) ? 2 : 0);

  const bf* Qb = (const bf*)(ws + OFF_Q) + (size_t)id * 49 * 32;
  const bf* Kb = (const bf*)(ws + OFF_K) + (size_t)id * 49 * 32;
  const bf* Vb = (const bf*)(ws + OFF_V) + (size_t)id * 32 * 64;
  const float* tbl = (const float*)(ws + OFF_TBL) + type * 4096;
  bf* O2 = (bf*)(ws + OFF_O2);

  int lane = threadIdx.x, l15 = lane & 15, g = lane >> 4;

  // S = Q K^T
  bf16x8 qf[4], kf[4];
#pragma unroll
  for (int mt = 0; mt < 4; ++mt) {
    int t = mt * 16 + l15; if (t > 48) t = 48;
    qf[mt] = ld8(Qb + t * 32 + g * 8);
  }
#pragma unroll
  for (int nt = 0; nt < 4; ++nt) {
    int t = nt * 16 + l15; if (t > 48) t = 48;
    kf[nt] = ld8(Kb + t * 32 + g * 8);
  }
  f32x4 s[4][4] = {};
#pragma unroll
  for (int mt = 0; mt < 4; ++mt)
#pragma unroll
    for (int nt = 0; nt < 4; ++nt) s[mt][nt] = MFMA16(qf[mt], kf[nt], s[mt][nt]);

  // scale + bias/mask table
#pragma unroll
  for (int mt = 0; mt < 4; ++mt)
#pragma unroll
    for (int nt = 0; nt < 4; ++nt)
#pragma unroll
      for (int r = 0; r < 4; ++r) {
        int row = mt * 16 + g * 4 + r, col = nt * 16 + l15;
        s[mt][nt][r] = s[mt][nt][r] * kScale + tbl[row * 64 + col];
      }

  // softmax per row (row lives across the 16 lanes sharing g)
#pragma unroll
  for (int mt = 0; mt < 4; ++mt) {
#pragma unroll
    for (int r = 0; r < 4; ++r) {
      float m = s[mt][0][r];
#pragma unroll
      for (int nt = 1; nt < 4; ++nt) m = fmaxf(m, s[mt][nt][r]);
#pragma unroll
      for (int off = 1; off < 16; off <<= 1) m = fmaxf(m, __shfl_xor(m, off));
      float p[4], sum = 0.0f;
#pragma unroll
      for (int nt = 0; nt < 4; ++nt) {
        p[nt] = __expf(s[mt][nt][r] - m);
        sum += p[nt];
      }
#pragma unroll
      for (int off = 1; off < 16; off <<= 1) sum += __shfl_xor(sum, off);
      float rinv = 1.0f / sum;
      int row = mt * 16 + g * 4 + r;
#pragma unroll
      for (int nt = 0; nt < 4; ++nt) P[row * 72 + nt * 16 + l15] = (bf)(p[nt] * rinv);
    }
  }
  __syncthreads();

  // O = P V   (A-frags from LDS P, B-frags from global V^T)
  f32x4 o[4][2] = {};
#pragma unroll
  for (int ks = 0; ks < 2; ++ks) {
    bf16x8 vf[2];
#pragma unroll
    for (int nt = 0; nt < 2; ++nt) vf[nt] = ld8(Vb + (nt * 16 + l15) * 64 + ks * 32 + g * 8);
#pragma unroll
    for (int mt = 0; mt < 4; ++mt) {
      bf16x8 pf = *reinterpret_cast<const bf16x8*>(&P[(mt * 16 + l15) * 72 + ks * 32 + g * 8]);
#pragma unroll
      for (int nt = 0; nt < 2; ++nt) o[mt][nt] = MFMA16(pf, vf[nt], o[mt][nt]);
    }
  }

  // write to spatial layout [b][h][w][head*32+d]
#pragma unroll
  for (int mt = 0; mt < 4; ++mt) {
#pragma unroll
    for (int r = 0; r < 4; ++r) {
      int t = mt * 16 + g * 4 + r;
      if (t < 49) {
        int tr = t / 7, tc = t % 7;
        int h = wh * 7 + tr, w = wwi * 7 + tc;
        bf* orow = O2 + (((size_t)b * 56 + h) * 56 + w) * 192 + head * 32;
        orow[l15] = (bf)o[mt][0][r];
        orow[l15 + 16] = (bf)o[mt][1][r];
      }
    }
  }
}

// ---------------- kernel 3: output projection + bias, inverse roll fused ----------------
// grid: 1568 blocks (64 rows each), 256 threads (wave = one 16-row M-tile)
__global__ __launch_bounds__(256) void proj_kernel(const float* __restrict__ bout,
                                                   char* __restrict__ ws,
                                                   float* __restrict__ out) {
  const bf* woutT = (const bf*)(ws + OFF_WOUTT);
  const bf* O2 = (const bf*)(ws + OFF_O2);
  int wave = threadIdx.x >> 6, lane = threadIdx.x & 63;
  int l15 = lane & 15, g = lane >> 4;
  int arow = blockIdx.x * 64 + wave * 16 + l15;

  f32x4 acc[12] = {};
#pragma unroll
  for (int ks = 0; ks < 6; ++ks) {
    bf16x8 a = ld8(O2 + (size_t)arow * 192 + ks * 32 + g * 8);
#pragma unroll
    for (int nt = 0; nt < 12; ++nt) {
      bf16x8 bfr = ld8(woutT + (nt * 16 + l15) * 192 + ks * 32 + g * 8);
      acc[nt] = MFMA16(a, bfr, acc[nt]);
    }
  }

#pragma unroll
  for (int nt = 0; nt < 12; ++nt) {
    int col = nt * 16 + l15;
    float bo = bout[col];
#pragma unroll
    for (int r = 0; r < 4; ++r) {
      int token = blockIdx.x * 64 + wave * 16 + g * 4 + r;
      int b = token / 3136, rem = token - b * 3136;
      int h = rem / 56, w = rem - h * 56;
      int hf = h + 3; if (hf >= 56) hf -= 56;
      int wf = w + 3; if (wf >= 56) wf -= 56;
      out[(((size_t)b * 56 + hf) * 56 + wf) * 192 + col] = acc[nt][r] + bo;
    }
  }
}

extern "C" void kernel_launch(void* const* d_in, const int* in_sizes, int n_in,
                              void* d_out, int out_size, void* d_ws, size_t ws_size,
                              hipStream_t stream) {
  const float* x = (const float*)d_in[0];
  const float* wqkv = (const float*)d_in[1];
  const float* wout = (const float*)d_in[2];
  const float* bout = (const float*)d_in[3];
  const float* pos = (const float*)d_in[4];
  char* ws = (char*)d_ws;

  hipLaunchKernelGGL(prep_kernel, dim3(128), dim3(256), 0, stream, wqkv, wout, pos, ws);
  hipLaunchKernelGGL(qkv_kernel, dim3(2048), dim3(256), 0, stream, x, ws);
  hipLaunchKernelGGL(attn_kernel, dim3(12288), dim3(64), 0, stream, ws);
  hipLaunchKernelGGL(proj_kernel, dim3(1568), dim3(256), 0, stream, bout, ws, (float*)d_out);
}

// Round 3
// 254.121 us; speedup vs baseline: 1.2282x; 1.2282x over previous
//
#include <hip/hip_runtime.h>
#include <hip/hip_bf16.h>

// WindowAttention (Swin shifted-window) fused kernel for MI355X.
// One block = one (batch, window): stage x -> QKV GEMM -> 6-head attention ->
// output projection, all through LDS. bf16 MFMA, f32 accum.
//
// Fragment layout (gfx950, verified by round-2 passing run):
//   A (16x32): lane l holds A[l&15][8*(l>>4)+j], j=0..7
//   B (32x16): lane l holds B[8*(l>>4)+j][l&15]
//   C/D      : lane l reg r -> C[4*(l>>4)+r][l&15]

typedef __bf16 bf16x8 __attribute__((ext_vector_type(8)));
typedef float f32x4 __attribute__((ext_vector_type(4)));
using bf = __bf16;

#define MFMA16(a, b, c) __builtin_amdgcn_mfma_f32_16x16x32_bf16((a), (b), (c), 0, 0, 0)

static constexpr float kNEG = -1000000000.0f;
static constexpr float kScale = 0.17677669529663687f;  // 32^-0.5

// workspace layout (bytes): read-only prep products
static constexpr size_t OFF_WQKVT = 0;        // bf16 [576][192]
static constexpr size_t OFF_WOUTT = 221184;   // bf16 [192][192]
static constexpr size_t OFF_TBL   = 294912;   // f32  [4][64][64]

// LDS layout (bytes). Strides keep 16B row alignment and <=2-way conflicts.
static constexpr int QK_STRIDE = 40;   // 80B rows: 20dw % 32 -> 2-way
static constexpr int VT_STRIDE = 72;   // 144B rows: 36dw % 32 = 4 -> 2-way
static constexpr int X_STRIDE  = 200;  // 400B rows: 100dw % 32 = 4 -> 2-way
static constexpr int O_STRIDE  = 200;
static constexpr int P_STRIDE  = 72;
static constexpr int R0_OFF = 0;                   // X [64][200] (25600) then Q [6][64][40] (30720)
static constexpr int R1_OFF = 30720;               // K  [6][64][40]  30720
static constexpr int R2_OFF = R1_OFF + 30720;      // VT [6][32][72]  27648
static constexpr int R3_OFF = R2_OFF + 27648;      // P  [8][16][72]  18432
static constexpr int R4_OFF = R3_OFF + 18432;      // O  [64][200]    25600
static constexpr int LDS_BYTES = R4_OFF + 25600;   // 133120 (<= 160K/CU)

// ---------------- kernel 0: weight transposes + bias/mask tables ----------------
__global__ void prep_kernel(const float* __restrict__ wqkv, const float* __restrict__ wout,
                            const float* __restrict__ pos, char* __restrict__ ws) {
  bf* wqkvT = (bf*)(ws + OFF_WQKVT);
  bf* woutT = (bf*)(ws + OFF_WOUTT);
  float* tbl = (float*)(ws + OFF_TBL);
  int tid = blockIdx.x * blockDim.x + threadIdx.x;
  int nthr = gridDim.x * blockDim.x;
  for (int i = tid; i < 192 * 576; i += nthr) {
    int k = i / 576, n = i % 576;
    wqkvT[n * 192 + k] = (bf)wqkv[i];
  }
  for (int i = tid; i < 192 * 192; i += nthr) {
    int k = i / 192, n = i % 192;
    woutT[n * 192 + k] = (bf)wout[i];
  }
  for (int i = tid; i < 4 * 64 * 64; i += nthr) {
    int type = i >> 12, rem = i & 4095, r = rem >> 6, c = rem & 63;
    float v;
    if (r < 49 && c < 49) {
      int ix = r / 7, iy = r % 7, jx = c / 7, jy = c % 7;
      v = pos[(jx - ix + 6) * 13 + (jy - iy + 6)];
      if ((type & 1) && ((r >= 28) != (c >= 28))) v += kNEG;  // ul mask
      if ((type & 2) && ((iy >= 4) != (jy >= 4))) v += kNEG;  // lr mask
    } else {
      v = kNEG;  // pad cols -> P=0; pad rows discarded
    }
    tbl[i] = v;
  }
}

// ---------------- fused kernel: 1 block = 1 window, 512 threads (8 waves) ----------------
__global__ __launch_bounds__(512) void fused_kernel(const float* __restrict__ x,
                                                    const float* __restrict__ bout,
                                                    const char* __restrict__ ws,
                                                    float* __restrict__ out) {
  __shared__ __align__(16) char smem[LDS_BYTES];
  bf* Xl = (bf*)(smem + R0_OFF);  // [64][200] (phase 1 only)
  bf* Ql = (bf*)(smem + R0_OFF);  // [6][64][40] (aliases X after barrier)
  bf* Kl = (bf*)(smem + R1_OFF);  // [6][64][40]
  bf* Vl = (bf*)(smem + R2_OFF);  // [6][32][72] (V^T: [head][d][t])
  bf* Pl = (bf*)(smem + R3_OFF);  // [8 waves][16][72]
  bf* Ol = (bf*)(smem + R4_OFF);  // [64][200]

  const bf* wqkvT = (const bf*)(ws + OFF_WQKVT);
  const bf* woutT = (const bf*)(ws + OFF_WOUTT);

  int bw = blockIdx.x;
  int b = bw >> 6, win = bw & 63;
  int wh = win >> 3, wwi = win & 7;
  int type = ((wh == 7) ? 1 : 0) | ((wwi == 7) ? 2 : 0);
  const float* tbl = (const float*)(ws + OFF_TBL) + type * 4096;

  int tid = threadIdx.x;
  int wave = tid >> 6, lane = tid & 63;
  int l15 = lane & 15, g = lane >> 4;
  int mrow = wave >> 2, ncol = wave & 3;  // phase-1/4 work split: 2M x 4N

  // ---- phase 0: stage x window -> LDS bf16 (roll fused), rows >=49 zeroed ----
#pragma unroll
  for (int it = 0; it < 3; ++it) {
    int chunk = it * 512 + tid;  // 64 rows * 24 chunks of 8
    int r = chunk / 24, c8 = (chunk % 24) * 8;
    bf16x8 v;
    if (r < 49) {
      int tr = r / 7, tc = r % 7;
      int h = wh * 7 + tr + 3; if (h >= 56) h -= 56;
      int w = wwi * 7 + tc + 3; if (w >= 56) w -= 56;
      const float* p = x + (((size_t)b * 56 + h) * 56 + w) * 192 + c8;
#pragma unroll
      for (int j = 0; j < 8; ++j) v[j] = (bf)p[j];
    } else {
#pragma unroll
      for (int j = 0; j < 8; ++j) v[j] = (bf)0.0f;
    }
    *(bf16x8*)(Xl + r * X_STRIDE + c8) = v;
  }
  __syncthreads();

  // ---- phase 1: QKV GEMM. wave = (mrow, ncol): rows [32*mrow,+32), cols [144*ncol,+144) ----
  f32x4 acc[2][9] = {};
#pragma unroll
  for (int ks = 0; ks < 6; ++ks) {
    bf16x8 a[2];
#pragma unroll
    for (int mt = 0; mt < 2; ++mt)
      a[mt] = *(const bf16x8*)(Xl + (mrow * 32 + mt * 16 + l15) * X_STRIDE + ks * 32 + g * 8);
#pragma unroll
    for (int nt = 0; nt < 9; ++nt) {
      bf16x8 bfr = *(const bf16x8*)(wqkvT + (size_t)(ncol * 144 + nt * 16 + l15) * 192 + ks * 32 + g * 8);
#pragma unroll
      for (int mt = 0; mt < 2; ++mt) acc[mt][nt] = MFMA16(a[mt], bfr, acc[mt][nt]);
    }
  }
  __syncthreads();  // X dead; safe to overwrite with Q

  // epilogue: scatter QKV into LDS (rows >=49 are exact zeros via zero-padded A)
#pragma unroll
  for (int nt = 0; nt < 9; ++nt) {
    int n = ncol * 144 + nt * 16 + l15;
    int s3 = n / 192;
    int hd = (n % 192) >> 5;
    int d = n & 31;
#pragma unroll
    for (int mt = 0; mt < 2; ++mt) {
#pragma unroll
      for (int r = 0; r < 4; ++r) {
        int t = mrow * 32 + mt * 16 + 4 * g + r;
        bf bv = (bf)acc[mt][nt][r];
        if (s3 == 0)      Ql[(hd * 64 + t) * QK_STRIDE + d] = bv;
        else if (s3 == 1) Kl[(hd * 64 + t) * QK_STRIDE + d] = bv;
        else              Vl[(hd * 32 + d) * VT_STRIDE + t] = bv;
      }
    }
  }
  __syncthreads();

  // ---- phase 3: attention. 24 items = (head 0..5) x (16-row quarter 0..3), 3 per wave ----
  for (int ii = 0; ii < 3; ++ii) {
    int item = wave + ii * 8;
    int head = item >> 2, mq = item & 3;
    const bf* Qh = Ql + head * 64 * QK_STRIDE;
    const bf* Kh = Kl + head * 64 * QK_STRIDE;
    const bf* Vh = Vl + head * 32 * VT_STRIDE;
    bf* Pw = Pl + wave * 16 * P_STRIDE;

    // S = Q K^T (16 rows x 64 cols, K-dim 32)
    bf16x8 qf = *(const bf16x8*)(Qh + (mq * 16 + l15) * QK_STRIDE + g * 8);
    f32x4 sa[4];
#pragma unroll
    for (int nt = 0; nt < 4; ++nt) {
      bf16x8 kf = *(const bf16x8*)(Kh + (nt * 16 + l15) * QK_STRIDE + g * 8);
      f32x4 z = {};
      sa[nt] = MFMA16(qf, kf, z);
    }
    // scale + bias/mask
#pragma unroll
    for (int nt = 0; nt < 4; ++nt)
#pragma unroll
      for (int r = 0; r < 4; ++r)
        sa[nt][r] = sa[nt][r] * kScale + tbl[(mq * 16 + 4 * g + r) * 64 + nt * 16 + l15];

    // softmax over 64 cols (row = 4g+r lives across 16 l15-lanes)
#pragma unroll
    for (int r = 0; r < 4; ++r) {
      float m = fmaxf(fmaxf(sa[0][r], sa[1][r]), fmaxf(sa[2][r], sa[3][r]));
#pragma unroll
      for (int off = 1; off < 16; off <<= 1) m = fmaxf(m, __shfl_xor(m, off));
      float p0 = __expf(sa[0][r] - m), p1 = __expf(sa[1][r] - m);
      float p2 = __expf(sa[2][r] - m), p3 = __expf(sa[3][r] - m);
      float sum = p0 + p1 + p2 + p3;
#pragma unroll
      for (int off = 1; off < 16; off <<= 1) sum += __shfl_xor(sum, off);
      float rinv = 1.0f / sum;
      int prow = 4 * g + r;
      Pw[prow * P_STRIDE + l15]      = (bf)(p0 * rinv);
      Pw[prow * P_STRIDE + 16 + l15] = (bf)(p1 * rinv);
      Pw[prow * P_STRIDE + 32 + l15] = (bf)(p2 * rinv);
      Pw[prow * P_STRIDE + 48 + l15] = (bf)(p3 * rinv);
    }
    asm volatile("s_waitcnt lgkmcnt(0)" ::: "memory");  // P visible to own wave's reads

    // O = P V  (16 rows x 32 d, K-dim 64 tokens)
    f32x4 o0 = {}, o1 = {};
#pragma unroll
    for (int ks = 0; ks < 2; ++ks) {
      bf16x8 pf = *(const bf16x8*)(Pw + l15 * P_STRIDE + ks * 32 + g * 8);
      bf16x8 v0 = *(const bf16x8*)(Vh + l15 * VT_STRIDE + ks * 32 + g * 8);
      bf16x8 v1 = *(const bf16x8*)(Vh + (16 + l15) * VT_STRIDE + ks * 32 + g * 8);
      o0 = MFMA16(pf, v0, o0);
      o1 = MFMA16(pf, v1, o1);
    }
#pragma unroll
    for (int r = 0; r < 4; ++r) {
      int orow = mq * 16 + 4 * g + r;
      Ol[orow * O_STRIDE + head * 32 + l15]      = (bf)o0[r];
      Ol[orow * O_STRIDE + head * 32 + 16 + l15] = (bf)o1[r];
    }
  }
  __syncthreads();

  // ---- phase 4: proj GEMM (64x192x192) + bias, inverse roll fused into stores ----
  f32x4 pacc[2][3] = {};
#pragma unroll
  for (int ks = 0; ks < 6; ++ks) {
    bf16x8 a0 = *(const bf16x8*)(Ol + (mrow * 32 + l15) * O_STRIDE + ks * 32 + g * 8);
    bf16x8 a1 = *(const bf16x8*)(Ol + (mrow * 32 + 16 + l15) * O_STRIDE + ks * 32 + g * 8);
#pragma unroll
    for (int nt = 0; nt < 3; ++nt) {
      bf16x8 bfr = *(const bf16x8*)(woutT + (size_t)(ncol * 48 + nt * 16 + l15) * 192 + ks * 32 + g * 8);
      pacc[0][nt] = MFMA16(a0, bfr, pacc[0][nt]);
      pacc[1][nt] = MFMA16(a1, bfr, pacc[1][nt]);
    }
  }
#pragma unroll
  for (int nt = 0; nt < 3; ++nt) {
    int col = ncol * 48 + nt * 16 + l15;
    float bo = bout[col];
#pragma unroll
    for (int mt = 0; mt < 2; ++mt) {
#pragma unroll
      for (int r = 0; r < 4; ++r) {
        int t = mrow * 32 + mt * 16 + 4 * g + r;
        if (t < 49) {
          int tr = t / 7, tc = t % 7;
          int h = wh * 7 + tr + 3; if (h >= 56) h -= 56;
          int w2 = wwi * 7 + tc + 3; if (w2 >= 56) w2 -= 56;
          out[(((size_t)b * 56 + h) * 56 + w2) * 192 + col] = pacc[mt][nt][r] + bo;
        }
      }
    }
  }
}

extern "C" void kernel_launch(void* const* d_in, const int* in_sizes, int n_in,
                              void* d_out, int out_size, void* d_ws, size_t ws_size,
                              hipStream_t stream) {
  const float* x = (const float*)d_in[0];
  const float* wqkv = (const float*)d_in[1];
  const float* wout = (const float*)d_in[2];
  const float* bout = (const float*)d_in[3];
  const float* pos = (const float*)d_in[4];
  char* ws = (char*)d_ws;

  hipLaunchKernelGGL(prep_kernel, dim3(128), dim3(256), 0, stream, wqkv, wout, pos, ws);
  hipLaunchKernelGGL(fused_kernel, dim3(2048), dim3(512), 0, stream,
                     x, bout, (const char*)ws, (float*)d_out);
}

// Round 4
// 192.863 us; speedup vs baseline: 1.6183x; 1.3176x over previous
//
#include <hip/hip_runtime.h>
#include <hip/hip_bf16.h>

// WindowAttention (Swin shifted-window) fused kernel for MI355X.
// One block = one (batch, window): stage x -> QKV GEMM -> 6-head attention ->
// output projection, all through LDS. bf16 MFMA, f32 accum.
// Round 4: 73KB LDS (region aliasing + 49-row tensors) -> 2 blocks/CU.
//
// Fragment layout (gfx950):
//   A (16x32): lane l holds A[l&15][8*(l>>4)+j], j=0..7
//   B (32x16): lane l holds B[8*(l>>4)+j][l&15]
//   C/D      : lane l reg r -> C[4*(l>>4)+r][l&15]

typedef __bf16 bf16x8 __attribute__((ext_vector_type(8)));
typedef float f32x4 __attribute__((ext_vector_type(4)));
using bf = __bf16;

#define MFMA16(a, b, c) __builtin_amdgcn_mfma_f32_16x16x32_bf16((a), (b), (c), 0, 0, 0)

static constexpr float kNEG = -1000000000.0f;
static constexpr float kScale = 0.17677669529663687f;  // 32^-0.5

// workspace layout (bytes): read-only prep products
static constexpr size_t OFF_WQKVT = 0;        // bf16 [576][192]
static constexpr size_t OFF_WOUTT = 221184;   // bf16 [192][192]
static constexpr size_t OFF_TBL   = 294912;   // f32  [4][64][64]

// LDS: three regions, time-multiplexed (all strides 16B-aligned, <=2-way conflicts)
//  R0 (23552B): X [49][200] -> Q [6][49][40] -> P [8][16][72]
//  R1 (23552B): K [6][49][40] -> O [49][200]
//  R2 (27648B): V^T [6][32][72]
static constexpr int QK_STRIDE = 40;
static constexpr int VT_STRIDE = 72;
static constexpr int X_STRIDE  = 200;
static constexpr int O_STRIDE  = 200;
static constexpr int P_STRIDE  = 72;
static constexpr int R0_OFF = 0;
static constexpr int R1_OFF = 23552;
static constexpr int R2_OFF = 47104;
static constexpr int LDS_BYTES = R2_OFF + 27648;  // 74752 B -> 2 blocks/CU

__device__ __forceinline__ unsigned pack2(float a, float b) {
  union { bf h[2]; unsigned u; } cv;
  cv.h[0] = (bf)a; cv.h[1] = (bf)b;
  return cv.u;
}

// ---------------- kernel 0: weight transposes + bias/mask tables ----------------
__global__ void prep_kernel(const float* __restrict__ wqkv, const float* __restrict__ wout,
                            const float* __restrict__ pos, char* __restrict__ ws) {
  bf* wqkvT = (bf*)(ws + OFF_WQKVT);
  bf* woutT = (bf*)(ws + OFF_WOUTT);
  float* tbl = (float*)(ws + OFF_TBL);
  int tid = blockIdx.x * blockDim.x + threadIdx.x;
  int nthr = gridDim.x * blockDim.x;
  for (int i = tid; i < 192 * 576; i += nthr) {
    int k = i / 576, n = i % 576;
    wqkvT[n * 192 + k] = (bf)wqkv[i];
  }
  for (int i = tid; i < 192 * 192; i += nthr) {
    int k = i / 192, n = i % 192;
    woutT[n * 192 + k] = (bf)wout[i];
  }
  for (int i = tid; i < 4 * 64 * 64; i += nthr) {
    int type = i >> 12, rem = i & 4095, r = rem >> 6, c = rem & 63;
    float v;
    if (r < 49 && c < 49) {
      int ix = r / 7, iy = r % 7, jx = c / 7, jy = c % 7;
      v = pos[(jx - ix + 6) * 13 + (jy - iy + 6)];
      if ((type & 1) && ((r >= 28) != (c >= 28))) v += kNEG;  // ul mask
      if ((type & 2) && ((iy >= 4) != (jy >= 4))) v += kNEG;  // lr mask
    } else {
      v = kNEG;  // pad cols -> P==0; pad rows discarded
    }
    tbl[i] = v;
  }
}

// ---------------- fused kernel: 1 block = 1 window, 512 threads (8 waves) ----------------
__global__ __launch_bounds__(512, 4) void fused_kernel(const float* __restrict__ x,
                                                       const float* __restrict__ bout,
                                                       const char* __restrict__ ws,
                                                       float* __restrict__ out) {
  __shared__ __align__(16) char smem[LDS_BYTES];
  bf* Xl = (bf*)(smem + R0_OFF);  // [49][200]
  bf* Ql = (bf*)(smem + R0_OFF);  // [6][49][40] (after X dead)
  bf* Pl = (bf*)(smem + R0_OFF);  // [8 waves][16][72] (after Q dead)
  bf* Kl = (bf*)(smem + R1_OFF);  // [6][49][40]
  bf* Ol = (bf*)(smem + R1_OFF);  // [49][200] (after K dead)
  bf* Vl = (bf*)(smem + R2_OFF);  // [6][32][72] (V^T: [head][d][t])

  const bf* wqkvT = (const bf*)(ws + OFF_WQKVT);
  const bf* woutT = (const bf*)(ws + OFF_WOUTT);

  int bw = blockIdx.x;
  int b = bw >> 6, win = bw & 63;
  int wh = win >> 3, wwi = win & 7;
  int type = ((wh == 7) ? 1 : 0) | ((wwi == 7) ? 2 : 0);
  const float* tbl = (const float*)(ws + OFF_TBL) + type * 4096;

  int tid = threadIdx.x;
  int wave = tid >> 6, lane = tid & 63;
  int l15 = lane & 15, g = lane >> 4;
  int mrow = wave >> 2, ncol = wave & 3;  // GEMM work split: 2M x 4N

  // ---- phase 0: stage x window -> LDS bf16 (roll fused), 49 rows ----
#pragma unroll
  for (int it = 0; it < 3; ++it) {
    int chunk = it * 512 + tid;  // 49 rows * 24 chunks of 8
    if (chunk < 1176) {
      int r = chunk / 24, c8 = (chunk % 24) * 8;
      int tr = r / 7, tc = r % 7;
      int h = wh * 7 + tr + 3; if (h >= 56) h -= 56;
      int w = wwi * 7 + tc + 3; if (w >= 56) w -= 56;
      const float* p = x + (((size_t)b * 56 + h) * 56 + w) * 192 + c8;
      bf16x8 v;
#pragma unroll
      for (int j = 0; j < 8; ++j) v[j] = (bf)p[j];
      *(bf16x8*)(Xl + r * X_STRIDE + c8) = v;
    }
  }
  __syncthreads();

  // ---- phase 1: QKV GEMM. wave (mrow,ncol): rows [32*mrow,+32), cols [144*ncol,+144) ----
  f32x4 acc[2][9] = {};
#pragma unroll
  for (int ks = 0; ks < 6; ++ks) {
    bf16x8 a[2];
#pragma unroll
    for (int mt = 0; mt < 2; ++mt) {
      int t = mrow * 32 + mt * 16 + l15; if (t > 48) t = 48;  // dup row 48; masked later
      a[mt] = *(const bf16x8*)(Xl + t * X_STRIDE + ks * 32 + g * 8);
    }
#pragma unroll
    for (int nt = 0; nt < 9; ++nt) {
      bf16x8 bfr = *(const bf16x8*)(wqkvT + (size_t)(ncol * 144 + nt * 16 + l15) * 192 + ks * 32 + g * 8);
#pragma unroll
      for (int mt = 0; mt < 2; ++mt) acc[mt][nt] = MFMA16(a[mt], bfr, acc[mt][nt]);
    }
  }
  __syncthreads();  // all X reads done; R0 becomes Q

  // ---- phase 2: epilogue scatter QKV into LDS ----
#pragma unroll
  for (int nt = 0; nt < 9; ++nt) {
    int n = ncol * 144 + nt * 16 + l15;
    int s3 = n / 192;
    int hd = (n % 192) >> 5;
    int d = n & 31;
#pragma unroll
    for (int mt = 0; mt < 2; ++mt) {
#pragma unroll
      for (int r = 0; r < 4; ++r) {
        int t = mrow * 32 + mt * 16 + 4 * g + r;
        bf bv = (bf)acc[mt][nt][r];
        if (s3 == 0)      { if (t < 49) Ql[(hd * 49 + t) * QK_STRIDE + d] = bv; }
        else if (s3 == 1) { if (t < 49) Kl[(hd * 49 + t) * QK_STRIDE + d] = bv; }
        else              { Vl[(hd * 32 + d) * VT_STRIDE + t] = bv; }  // t>=49: dup, killed by P==0
      }
    }
  }
  __syncthreads();

  // ---- phase 3a: S = QK^T, bias/mask, softmax; P packed bf16 in regs ----
  // 24 items = (head 0..5) x (16-row quarter 0..3); 3 per wave.
  unsigned pp[3][8];   // per item: 16 bf16 = P[4g+r][nt*16+l15], idx nt*4+r packed (p0,p1),(p2,p3)
#pragma unroll
  for (int ii = 0; ii < 3; ++ii) {
    int item = wave + ii * 8;
    int head = item >> 2, mq = item & 3;
    const bf* Qh = Ql + head * 49 * QK_STRIDE;
    const bf* Kh = Kl + head * 49 * QK_STRIDE;

    int tq = mq * 16 + l15; if (tq > 48) tq = 48;
    bf16x8 qf = *(const bf16x8*)(Qh + tq * QK_STRIDE + g * 8);
    f32x4 sa[4];
#pragma unroll
    for (int nt = 0; nt < 4; ++nt) {
      int tk = nt * 16 + l15; if (tk > 48) tk = 48;
      bf16x8 kf = *(const bf16x8*)(Kh + tk * QK_STRIDE + g * 8);
      f32x4 z = {};
      sa[nt] = MFMA16(qf, kf, z);
    }
#pragma unroll
    for (int nt = 0; nt < 4; ++nt)
#pragma unroll
      for (int r = 0; r < 4; ++r)
        sa[nt][r] = sa[nt][r] * kScale + tbl[(mq * 16 + 4 * g + r) * 64 + nt * 16 + l15];

#pragma unroll
    for (int r = 0; r < 4; ++r) {
      float m = fmaxf(fmaxf(sa[0][r], sa[1][r]), fmaxf(sa[2][r], sa[3][r]));
#pragma unroll
      for (int off = 1; off < 16; off <<= 1) m = fmaxf(m, __shfl_xor(m, off));
      float p0 = __expf(sa[0][r] - m), p1 = __expf(sa[1][r] - m);
      float p2 = __expf(sa[2][r] - m), p3 = __expf(sa[3][r] - m);
      float sum = p0 + p1 + p2 + p3;
#pragma unroll
      for (int off = 1; off < 16; off <<= 1) sum += __shfl_xor(sum, off);
      float rinv = 1.0f / sum;
      pp[ii][r * 2]     = pack2(p0 * rinv, p1 * rinv);
      pp[ii][r * 2 + 1] = pack2(p2 * rinv, p3 * rinv);
    }
  }
  __syncthreads();  // Q,K dead; R0 -> P, R1 -> O

  // ---- phase 3b: P through LDS (transpose), O = P V ----
  bf* Pw = Pl + wave * 16 * P_STRIDE;
  for (int ii = 0; ii < 3; ++ii) {
    int item = wave + ii * 8;
    int head = item >> 2, mq = item & 3;
    const bf* Vh = Vl + head * 32 * VT_STRIDE;

#pragma unroll
    for (int r = 0; r < 4; ++r) {
      int prow = 4 * g + r;
      union { unsigned u; bf h[2]; } ua, ub;
      ua.u = pp[ii][r * 2]; ub.u = pp[ii][r * 2 + 1];
      Pw[prow * P_STRIDE + l15]      = ua.h[0];
      Pw[prow * P_STRIDE + 16 + l15] = ua.h[1];
      Pw[prow * P_STRIDE + 32 + l15] = ub.h[0];
      Pw[prow * P_STRIDE + 48 + l15] = ub.h[1];
    }
    asm volatile("s_waitcnt lgkmcnt(0)" ::: "memory");  // per-wave P buffer RAW
    __builtin_amdgcn_sched_barrier(0);

    f32x4 o0 = {}, o1 = {};
#pragma unroll
    for (int ks = 0; ks < 2; ++ks) {
      bf16x8 pf = *(const bf16x8*)(Pw + l15 * P_STRIDE + ks * 32 + g * 8);
      bf16x8 v0 = *(const bf16x8*)(Vh + l15 * VT_STRIDE + ks * 32 + g * 8);
      bf16x8 v1 = *(const bf16x8*)(Vh + (16 + l15) * VT_STRIDE + ks * 32 + g * 8);
      o0 = MFMA16(pf, v0, o0);
      o1 = MFMA16(pf, v1, o1);
    }
#pragma unroll
    for (int r = 0; r < 4; ++r) {
      int orow = mq * 16 + 4 * g + r;
      if (orow < 49) {
        Ol[orow * O_STRIDE + head * 32 + l15]      = (bf)o0[r];
        Ol[orow * O_STRIDE + head * 32 + 16 + l15] = (bf)o1[r];
      }
    }
    asm volatile("s_waitcnt lgkmcnt(0)" ::: "memory");  // drain before next item reuses Pw
    __builtin_amdgcn_sched_barrier(0);
  }
  __syncthreads();

  // ---- phase 4: proj GEMM (49x192x192) + bias, inverse roll fused into stores ----
  f32x4 pacc[2][3] = {};
#pragma unroll
  for (int ks = 0; ks < 6; ++ks) {
    int t0 = mrow * 32 + l15;      if (t0 > 48) t0 = 48;
    int t1 = mrow * 32 + 16 + l15; if (t1 > 48) t1 = 48;
    bf16x8 a0 = *(const bf16x8*)(Ol + t0 * O_STRIDE + ks * 32 + g * 8);
    bf16x8 a1 = *(const bf16x8*)(Ol + t1 * O_STRIDE + ks * 32 + g * 8);
#pragma unroll
    for (int nt = 0; nt < 3; ++nt) {
      bf16x8 bfr = *(const bf16x8*)(woutT + (size_t)(ncol * 48 + nt * 16 + l15) * 192 + ks * 32 + g * 8);
      pacc[0][nt] = MFMA16(a0, bfr, pacc[0][nt]);
      pacc[1][nt] = MFMA16(a1, bfr, pacc[1][nt]);
    }
  }
#pragma unroll
  for (int nt = 0; nt < 3; ++nt) {
    int col = ncol * 48 + nt * 16 + l15;
    float bo = bout[col];
#pragma unroll
    for (int mt = 0; mt < 2; ++mt) {
#pragma unroll
      for (int r = 0; r < 4; ++r) {
        int t = mrow * 32 + mt * 16 + 4 * g + r;
        if (t < 49) {
          int tr = t / 7, tc = t % 7;
          int h = wh * 7 + tr + 3; if (h >= 56) h -= 56;
          int w2 = wwi * 7 + tc + 3; if (w2 >= 56) w2 -= 56;
          out[(((size_t)b * 56 + h) * 56 + w2) * 192 + col] = pacc[mt][nt][r] + bo;
        }
      }
    }
  }
}

extern "C" void kernel_launch(void* const* d_in, const int* in_sizes, int n_in,
                              void* d_out, int out_size, void* d_ws, size_t ws_size,
                              hipStream_t stream) {
  const float* x = (const float*)d_in[0];
  const float* wqkv = (const float*)d_in[1];
  const float* wout = (const float*)d_in[2];
  const float* bout = (const float*)d_in[3];
  const float* pos = (const float*)d_in[4];
  char* ws = (char*)d_ws;

  hipLaunchKernelGGL(prep_kernel, dim3(128), dim3(256), 0, stream, wqkv, wout, pos, ws);
  hipLaunchKernelGGL(fused_kernel, dim3(2048), dim3(512), 0, stream,
                     x, bout, (const char*)ws, (float*)d_out);
}

// Round 5
// 179.985 us; speedup vs baseline: 1.7341x; 1.0716x over previous
//
#include <hip/hip_runtime.h>
#include <hip/hip_bf16.h>

// WindowAttention (Swin shifted-window) fused kernel for MI355X.
// One block = one (batch, window): stage x -> QKV GEMM (2-pass, spill-free) ->
// 6-head attention (LDS bias table) -> output projection. bf16 MFMA, f32 accum.
//
// Fragment layout (gfx950):
//   A (16x32): lane l holds A[l&15][8*(l>>4)+j], j=0..7
//   B (32x16): lane l holds B[8*(l>>4)+j][l&15]
//   C/D      : lane l reg r -> C[4*(l>>4)+r][l&15]

typedef __bf16 bf16x8 __attribute__((ext_vector_type(8)));
typedef __bf16 bf16x4 __attribute__((ext_vector_type(4)));
typedef float f32x4 __attribute__((ext_vector_type(4)));
using bf = __bf16;

#define MFMA16(a, b, c) __builtin_amdgcn_mfma_f32_16x16x32_bf16((a), (b), (c), 0, 0, 0)

static constexpr float kNEG = -1000000000.0f;
static constexpr float kScale = 0.17677669529663687f;  // 32^-0.5

// workspace layout (bytes): read-only prep products
static constexpr size_t OFF_WQKVT = 0;        // bf16 [576][192]
static constexpr size_t OFF_WOUTT = 221184;   // bf16 [192][192]
static constexpr size_t OFF_TBL   = 294912;   // f32  [4][64][64]

// LDS: regions time-multiplexed (strides keep 16B row alignment, <=2-way conflicts)
//  R0: X [49][200] -> Q [6][49][40] -> P [8 waves][16][72]
//  R1: K [6][49][40] -> O [49][200]
//  R2: V^T [6][32][72]
//  TB: bias table bf16 [49][68] (stride 68 -> conflict-free scalar reads)
static constexpr int QK_STRIDE = 40;
static constexpr int VT_STRIDE = 72;
static constexpr int X_STRIDE  = 200;
static constexpr int O_STRIDE  = 200;
static constexpr int P_STRIDE  = 72;
static constexpr int TB_STRIDE = 68;
static constexpr int R0_OFF = 0;
static constexpr int R1_OFF = 23552;
static constexpr int R2_OFF = 47104;
static constexpr int TB_OFF = 74752;
static constexpr int LDS_BYTES = TB_OFF + 49 * TB_STRIDE * 2 + 8;  // 81424 -> 2 blocks/CU

__device__ __forceinline__ unsigned pack2(float a, float b) {
  union { bf h[2]; unsigned u; } cv;
  cv.h[0] = (bf)a; cv.h[1] = (bf)b;
  return cv.u;
}

// ---------------- kernel 0: weight transposes + bias/mask tables ----------------
__global__ void prep_kernel(const float* __restrict__ wqkv, const float* __restrict__ wout,
                            const float* __restrict__ pos, char* __restrict__ ws) {
  bf* wqkvT = (bf*)(ws + OFF_WQKVT);
  bf* woutT = (bf*)(ws + OFF_WOUTT);
  float* tbl = (float*)(ws + OFF_TBL);
  int tid = blockIdx.x * blockDim.x + threadIdx.x;
  int nthr = gridDim.x * blockDim.x;
  for (int i = tid; i < 192 * 576; i += nthr) {
    int k = i / 576, n = i % 576;
    wqkvT[n * 192 + k] = (bf)wqkv[i];
  }
  for (int i = tid; i < 192 * 192; i += nthr) {
    int k = i / 192, n = i % 192;
    woutT[n * 192 + k] = (bf)wout[i];
  }
  for (int i = tid; i < 4 * 64 * 64; i += nthr) {
    int type = i >> 12, rem = i & 4095, r = rem >> 6, c = rem & 63;
    float v;
    if (r < 49 && c < 49) {
      int ix = r / 7, iy = r % 7, jx = c / 7, jy = c % 7;
      v = pos[(jx - ix + 6) * 13 + (jy - iy + 6)];
      if ((type & 1) && ((r >= 28) != (c >= 28))) v += kNEG;  // ul mask
      if ((type & 2) && ((iy >= 4) != (jy >= 4))) v += kNEG;  // lr mask
    } else {
      v = kNEG;  // pad cols -> P==0; pad rows discarded
    }
    tbl[i] = v;
  }
}

// ---------------- fused kernel: 1 block = 1 window, 512 threads (8 waves) ----------------
__global__ __launch_bounds__(512, 4) void fused_kernel(const float* __restrict__ x,
                                                       const float* __restrict__ bout,
                                                       const char* __restrict__ ws,
                                                       float* __restrict__ out) {
  __shared__ __align__(16) char smem[LDS_BYTES];
  bf* Xl = (bf*)(smem + R0_OFF);  // [49][200]
  bf* Ql = (bf*)(smem + R0_OFF);  // [6][49][40] (after X dead)
  bf* Pl = (bf*)(smem + R0_OFF);  // [8 waves][16][72] (after Q dead)
  bf* Kl = (bf*)(smem + R1_OFF);  // [6][49][40]
  bf* Ol = (bf*)(smem + R1_OFF);  // [49][200] (after K dead)
  bf* Vl = (bf*)(smem + R2_OFF);  // [6][32][72] (V^T: [head][d][t])
  bf* Tb = (bf*)(smem + TB_OFF);  // [49][68]

  const bf* wqkvT = (const bf*)(ws + OFF_WQKVT);
  const bf* woutT = (const bf*)(ws + OFF_WOUTT);

  int bw = blockIdx.x;
  int b = bw >> 6, win = bw & 63;
  int wh = win >> 3, wwi = win & 7;
  int type = ((wh == 7) ? 1 : 0) | ((wwi == 7) ? 2 : 0);
  const float* tblg = (const float*)(ws + OFF_TBL) + type * 4096;

  int tid = threadIdx.x;
  int wave = tid >> 6, lane = tid & 63;
  int l15 = lane & 15, g = lane >> 4;
  int mrow = wave >> 2, ncol = wave & 3;  // GEMM work split: 2M x 4N

  // ---- phase 0: stage x window (roll fused) + bias table -> LDS bf16 ----
#pragma unroll
  for (int it = 0; it < 3; ++it) {
    int chunk = it * 512 + tid;  // 49 rows * 24 chunks of 8
    if (chunk < 1176) {
      int r = chunk / 24, c8 = (chunk % 24) * 8;
      int tr = r / 7, tc = r % 7;
      int h = wh * 7 + tr + 3; if (h >= 56) h -= 56;
      int w = wwi * 7 + tc + 3; if (w >= 56) w -= 56;
      const float* p = x + (((size_t)b * 56 + h) * 56 + w) * 192 + c8;
      bf16x8 v;
#pragma unroll
      for (int j = 0; j < 8; ++j) v[j] = (bf)p[j];
      *(bf16x8*)(Xl + r * X_STRIDE + c8) = v;
    }
  }
  if (tid < 392) {  // 49 rows x 8 chunks of 8 cols
    int r = tid >> 3, c8 = (tid & 7) * 8;
    const float* p = tblg + r * 64 + c8;
    bf16x4 v0, v1;
#pragma unroll
    for (int j = 0; j < 4; ++j) { v0[j] = (bf)p[j]; v1[j] = (bf)p[4 + j]; }
    *(bf16x4*)(Tb + r * TB_STRIDE + c8) = v0;      // 8B-aligned (136*r + 16*c)
    *(bf16x4*)(Tb + r * TB_STRIDE + c8 + 4) = v1;
  }
  __syncthreads();

  // ---- phase 1a: K,V columns. wave ncol: cols [192 + 96*ncol, +96), rows [32*mrow,+32) ----
  {
    f32x4 acc[2][6] = {};
#pragma unroll
    for (int ks = 0; ks < 6; ++ks) {
      bf16x8 a[2];
#pragma unroll
      for (int mt = 0; mt < 2; ++mt) {
        int t = mrow * 32 + mt * 16 + l15; if (t > 48) t = 48;  // dup row; masked later
        a[mt] = *(const bf16x8*)(Xl + t * X_STRIDE + ks * 32 + g * 8);
      }
#pragma unroll
      for (int nt = 0; nt < 6; ++nt) {
        int n = 192 + ncol * 96 + nt * 16 + l15;
        bf16x8 bfr = *(const bf16x8*)(wqkvT + (size_t)n * 192 + ks * 32 + g * 8);
#pragma unroll
        for (int mt = 0; mt < 2; ++mt) acc[mt][nt] = MFMA16(a[mt], bfr, acc[mt][nt]);
      }
    }
    // scatter K,V into R1/R2 (disjoint from X in R0 -> no barrier needed)
#pragma unroll
    for (int nt = 0; nt < 6; ++nt) {
      int n = 192 + ncol * 96 + nt * 16 + l15;
      int s3 = n / 192;               // 1 = K, 2 = V
      int lc = n - s3 * 192;
      int hd = lc >> 5, d = lc & 31;
#pragma unroll
      for (int mt = 0; mt < 2; ++mt) {
#pragma unroll
        for (int r = 0; r < 4; ++r) {
          int t = mrow * 32 + mt * 16 + 4 * g + r;
          bf bv = (bf)acc[mt][nt][r];
          if (s3 == 1) { if (t < 49) Kl[(hd * 49 + t) * QK_STRIDE + d] = bv; }
          else         { Vl[(hd * 32 + d) * VT_STRIDE + t] = bv; }  // t>=49 dup, killed by P==0
        }
      }
    }
  }

  // ---- phase 1b: Q columns. wave ncol: cols [48*ncol, +48) ----
  {
    f32x4 qacc[2][3] = {};
#pragma unroll
    for (int ks = 0; ks < 6; ++ks) {
      bf16x8 a[2];
#pragma unroll
      for (int mt = 0; mt < 2; ++mt) {
        int t = mrow * 32 + mt * 16 + l15; if (t > 48) t = 48;
        a[mt] = *(const bf16x8*)(Xl + t * X_STRIDE + ks * 32 + g * 8);
      }
#pragma unroll
      for (int nt = 0; nt < 3; ++nt) {
        int n = ncol * 48 + nt * 16 + l15;
        bf16x8 bfr = *(const bf16x8*)(wqkvT + (size_t)n * 192 + ks * 32 + g * 8);
#pragma unroll
        for (int mt = 0; mt < 2; ++mt) qacc[mt][nt] = MFMA16(a[mt], bfr, qacc[mt][nt]);
      }
    }
    __syncthreads();  // all X reads done; R0 becomes Q
#pragma unroll
    for (int nt = 0; nt < 3; ++nt) {
      int n = ncol * 48 + nt * 16 + l15;
      int hd = n >> 5, d = n & 31;
#pragma unroll
      for (int mt = 0; mt < 2; ++mt) {
#pragma unroll
        for (int r = 0; r < 4; ++r) {
          int t = mrow * 32 + mt * 16 + 4 * g + r;
          if (t < 49) Ql[(hd * 49 + t) * QK_STRIDE + d] = (bf)qacc[mt][nt][r];
        }
      }
    }
  }
  __syncthreads();

  // ---- phase 3a: S = QK^T, bias/mask, softmax; P packed bf16 in regs ----
  // 24 items = (head 0..5) x (16-row quarter 0..3); 3 per wave.
  unsigned pp[3][8];
#pragma unroll
  for (int ii = 0; ii < 3; ++ii) {
    int item = wave + ii * 8;
    int head = item >> 2, mq = item & 3;
    const bf* Qh = Ql + head * 49 * QK_STRIDE;
    const bf* Kh = Kl + head * 49 * QK_STRIDE;

    int tq = mq * 16 + l15; if (tq > 48) tq = 48;
    bf16x8 qf = *(const bf16x8*)(Qh + tq * QK_STRIDE + g * 8);
    f32x4 sa[4];
#pragma unroll
    for (int nt = 0; nt < 4; ++nt) {
      int tk = nt * 16 + l15; if (tk > 48) tk = 48;
      bf16x8 kf = *(const bf16x8*)(Kh + tk * QK_STRIDE + g * 8);
      f32x4 z = {};
      sa[nt] = MFMA16(qf, kf, z);
    }
    // scale + bias/mask from LDS table (row clamped; garbage rows discarded)
#pragma unroll
    for (int r = 0; r < 4; ++r) {
      int rowc = mq * 16 + 4 * g + r; if (rowc > 48) rowc = 48;
      const bf* trow = Tb + rowc * TB_STRIDE + l15;
#pragma unroll
      for (int nt = 0; nt < 4; ++nt)
        sa[nt][r] = sa[nt][r] * kScale + (float)trow[nt * 16];
    }

#pragma unroll
    for (int r = 0; r < 4; ++r) {
      float m = fmaxf(fmaxf(sa[0][r], sa[1][r]), fmaxf(sa[2][r], sa[3][r]));
#pragma unroll
      for (int off = 1; off < 16; off <<= 1) m = fmaxf(m, __shfl_xor(m, off));
      float p0 = __expf(sa[0][r] - m), p1 = __expf(sa[1][r] - m);
      float p2 = __expf(sa[2][r] - m), p3 = __expf(sa[3][r] - m);
      float sum = p0 + p1 + p2 + p3;
#pragma unroll
      for (int off = 1; off < 16; off <<= 1) sum += __shfl_xor(sum, off);
      float rinv = 1.0f / sum;
      pp[ii][r * 2]     = pack2(p0 * rinv, p1 * rinv);
      pp[ii][r * 2 + 1] = pack2(p2 * rinv, p3 * rinv);
    }
  }
  __syncthreads();  // Q,K dead; R0 -> P, R1 -> O

  // ---- phase 3b: P through LDS (transpose), O = P V ----
  bf* Pw = Pl + wave * 16 * P_STRIDE;
  for (int ii = 0; ii < 3; ++ii) {
    int item = wave + ii * 8;
    int head = item >> 2, mq = item & 3;
    const bf* Vh = Vl + head * 32 * VT_STRIDE;

#pragma unroll
    for (int r = 0; r < 4; ++r) {
      int prow = 4 * g + r;
      union { unsigned u; bf h[2]; } ua, ub;
      ua.u = pp[ii][r * 2]; ub.u = pp[ii][r * 2 + 1];
      Pw[prow * P_STRIDE + l15]      = ua.h[0];
      Pw[prow * P_STRIDE + 16 + l15] = ua.h[1];
      Pw[prow * P_STRIDE + 32 + l15] = ub.h[0];
      Pw[prow * P_STRIDE + 48 + l15] = ub.h[1];
    }
    asm volatile("s_waitcnt lgkmcnt(0)" ::: "memory");  // per-wave P buffer RAW
    __builtin_amdgcn_sched_barrier(0);

    f32x4 o0 = {}, o1 = {};
#pragma unroll
    for (int ks = 0; ks < 2; ++ks) {
      bf16x8 pf = *(const bf16x8*)(Pw + l15 * P_STRIDE + ks * 32 + g * 8);
      bf16x8 v0 = *(const bf16x8*)(Vh + l15 * VT_STRIDE + ks * 32 + g * 8);
      bf16x8 v1 = *(const bf16x8*)(Vh + (16 + l15) * VT_STRIDE + ks * 32 + g * 8);
      o0 = MFMA16(pf, v0, o0);
      o1 = MFMA16(pf, v1, o1);
    }
#pragma unroll
    for (int r = 0; r < 4; ++r) {
      int orow = mq * 16 + 4 * g + r;
      if (orow < 49) {
        Ol[orow * O_STRIDE + head * 32 + l15]      = (bf)o0[r];
        Ol[orow * O_STRIDE + head * 32 + 16 + l15] = (bf)o1[r];
      }
    }
    asm volatile("s_waitcnt lgkmcnt(0)" ::: "memory");  // drain before next item reuses Pw
    __builtin_amdgcn_sched_barrier(0);
  }
  __syncthreads();

  // ---- phase 4: proj GEMM (49x192x192) + bias, inverse roll fused into stores ----
  f32x4 pacc[2][3] = {};
#pragma unroll
  for (int ks = 0; ks < 6; ++ks) {
    int t0 = mrow * 32 + l15;      if (t0 > 48) t0 = 48;
    int t1 = mrow * 32 + 16 + l15; if (t1 > 48) t1 = 48;
    bf16x8 a0 = *(const bf16x8*)(Ol + t0 * O_STRIDE + ks * 32 + g * 8);
    bf16x8 a1 = *(const bf16x8*)(Ol + t1 * O_STRIDE + ks * 32 + g * 8);
#pragma unroll
    for (int nt = 0; nt < 3; ++nt) {
      bf16x8 bfr = *(const bf16x8*)(woutT + (size_t)(ncol * 48 + nt * 16 + l15) * 192 + ks * 32 + g * 8);
      pacc[0][nt] = MFMA16(a0, bfr, pacc[0][nt]);
      pacc[1][nt] = MFMA16(a1, bfr, pacc[1][nt]);
    }
  }
#pragma unroll
  for (int nt = 0; nt < 3; ++nt) {
    int col = ncol * 48 + nt * 16 + l15;
    float bo = bout[col];
#pragma unroll
    for (int mt = 0; mt < 2; ++mt) {
#pragma unroll
      for (int r = 0; r < 4; ++r) {
        int t = mrow * 32 + mt * 16 + 4 * g + r;
        if (t < 49) {
          int tr = t / 7, tc = t % 7;
          int h = wh * 7 + tr + 3; if (h >= 56) h -= 56;
          int w2 = wwi * 7 + tc + 3; if (w2 >= 56) w2 -= 56;
          out[(((size_t)b * 56 + h) * 56 + w2) * 192 + col] = pacc[mt][nt][r] + bo;
        }
      }
    }
  }
}

extern "C" void kernel_launch(void* const* d_in, const int* in_sizes, int n_in,
                              void* d_out, int out_size, void* d_ws, size_t ws_size,
                              hipStream_t stream) {
  const float* x = (const float*)d_in[0];
  const float* wqkv = (const float*)d_in[1];
  const float* wout = (const float*)d_in[2];
  const float* bout = (const float*)d_in[3];
  const float* pos = (const float*)d_in[4];
  char* ws = (char*)d_ws;

  hipLaunchKernelGGL(prep_kernel, dim3(128), dim3(256), 0, stream, wqkv, wout, pos, ws);
  hipLaunchKernelGGL(fused_kernel, dim3(2048), dim3(512), 0, stream,
                     x, bout, (const char*)ws, (float*)d_out);
}

// Round 6
// 172.867 us; speedup vs baseline: 1.8055x; 1.0412x over previous
//
#include <hip/hip_runtime.h>
#include <hip/hip_bf16.h>

// WindowAttention (Swin shifted-window) fused kernel for MI355X.
// One block = one (batch, window): stage x -> QKV GEMM (2-pass) ->
// 6-head attention (swapped QK^T, lane-local softmax, zero-shuffle PV) ->
// output projection. bf16 MFMA, f32 accum.
//
// Fragment layout (gfx950):
//   A (16x32): lane l holds A[l&15][8*(l>>4)+j], j=0..7
//   B (32x16): lane l holds B[8*(l>>4)+j][l&15]
//   C/D      : lane l reg r -> C[4*(l>>4)+r][l&15]
//
// Attention trick: compute S^T = K·Q^T with tile T loading K rows
//   kt(T,m) = 8*(m>>2) + 4*(T&1) + 32*(T>>1) + (m&3)
// so lane (l15,g) holds S^T[kt = g*8 + 4*(T&1) + 32*(T>>1) + r][q = l15]:
// all 16 values share q=l15 (softmax = local sum + 2 shfl_xor), and the
// 4 packed quads are exactly the PV A-frag slices (no cross-lane exchange).

typedef __bf16 bf16x8 __attribute__((ext_vector_type(8)));
typedef __bf16 bf16x4 __attribute__((ext_vector_type(4)));
typedef float f32x4 __attribute__((ext_vector_type(4)));
using bf = __bf16;

#define MFMA16(a, b, c) __builtin_amdgcn_mfma_f32_16x16x32_bf16((a), (b), (c), 0, 0, 0)

static constexpr float kNEG = -1000000000.0f;
static constexpr float kScale = 0.17677669529663687f;  // 32^-0.5

// workspace layout (bytes): read-only prep products
static constexpr size_t OFF_WQKVT = 0;        // bf16 [576][192]
static constexpr size_t OFF_WOUTT = 221184;   // bf16 [192][192]
static constexpr size_t OFF_TBL   = 294912;   // f32  [4][64][64]

// LDS: regions time-multiplexed
//  R0: X [49][200] -> Q [6][49][40]
//  R1: K [6][49][40] -> O [49][200]
//  R2: V^T [6][32][72]
//  TB: bias table bf16 [49][68]
static constexpr int QK_STRIDE = 40;
static constexpr int VT_STRIDE = 72;
static constexpr int X_STRIDE  = 200;
static constexpr int O_STRIDE  = 200;
static constexpr int TB_STRIDE = 68;
static constexpr int R0_OFF = 0;
static constexpr int R1_OFF = 23552;
static constexpr int R2_OFF = 47104;
static constexpr int TB_OFF = 74752;
static constexpr int LDS_BYTES = TB_OFF + 49 * TB_STRIDE * 2 + 8;  // 81424 -> 2 blocks/CU

__device__ __forceinline__ unsigned pack2(float a, float b) {
  union { bf h[2]; unsigned u; } cv;
  cv.h[0] = (bf)a; cv.h[1] = (bf)b;
  return cv.u;
}

// ---------------- kernel 0: weight transposes + bias/mask tables ----------------
__global__ void prep_kernel(const float* __restrict__ wqkv, const float* __restrict__ wout,
                            const float* __restrict__ pos, char* __restrict__ ws) {
  bf* wqkvT = (bf*)(ws + OFF_WQKVT);
  bf* woutT = (bf*)(ws + OFF_WOUTT);
  float* tbl = (float*)(ws + OFF_TBL);
  int tid = blockIdx.x * blockDim.x + threadIdx.x;
  int nthr = gridDim.x * blockDim.x;
  for (int i = tid; i < 192 * 576; i += nthr) {
    int k = i / 576, n = i % 576;
    wqkvT[n * 192 + k] = (bf)wqkv[i];
  }
  for (int i = tid; i < 192 * 192; i += nthr) {
    int k = i / 192, n = i % 192;
    woutT[n * 192 + k] = (bf)wout[i];
  }
  for (int i = tid; i < 4 * 64 * 64; i += nthr) {
    int type = i >> 12, rem = i & 4095, r = rem >> 6, c = rem & 63;
    float v;
    if (r < 49 && c < 49) {
      int ix = r / 7, iy = r % 7, jx = c / 7, jy = c % 7;
      v = pos[(jx - ix + 6) * 13 + (jy - iy + 6)];
      if ((type & 1) && ((r >= 28) != (c >= 28))) v += kNEG;  // ul mask
      if ((type & 2) && ((iy >= 4) != (jy >= 4))) v += kNEG;  // lr mask
    } else {
      v = kNEG;  // pad cols -> P==0; pad rows discarded
    }
    tbl[i] = v;
  }
}

// ---------------- fused kernel: 1 block = 1 window, 512 threads (8 waves) ----------------
__global__ __launch_bounds__(512, 4) void fused_kernel(const float* __restrict__ x,
                                                       const float* __restrict__ bout,
                                                       const char* __restrict__ ws,
                                                       float* __restrict__ out) {
  __shared__ __align__(16) char smem[LDS_BYTES];
  bf* Xl = (bf*)(smem + R0_OFF);  // [49][200]
  bf* Ql = (bf*)(smem + R0_OFF);  // [6][49][40] (after X dead)
  bf* Kl = (bf*)(smem + R1_OFF);  // [6][49][40]
  bf* Ol = (bf*)(smem + R1_OFF);  // [49][200] (after K dead)
  bf* Vl = (bf*)(smem + R2_OFF);  // [6][32][72] (V^T: [head][d][t])
  bf* Tb = (bf*)(smem + TB_OFF);  // [49][68], cols 49..63 = NEG

  const bf* wqkvT = (const bf*)(ws + OFF_WQKVT);
  const bf* woutT = (const bf*)(ws + OFF_WOUTT);

  int bw = blockIdx.x;
  int b = bw >> 6, win = bw & 63;
  int wh = win >> 3, wwi = win & 7;
  int type = ((wh == 7) ? 1 : 0) | ((wwi == 7) ? 2 : 0);
  const float* tblg = (const float*)(ws + OFF_TBL) + type * 4096;

  int tid = threadIdx.x;
  int wave = tid >> 6, lane = tid & 63;
  int l15 = lane & 15, g = lane >> 4;
  int mrow = wave >> 2, ncol = wave & 3;  // GEMM work split: 2M x 4N

  // ---- phase 0: stage x window (roll fused) + bias table -> LDS bf16 ----
#pragma unroll
  for (int it = 0; it < 3; ++it) {
    int chunk = it * 512 + tid;  // 49 rows * 24 chunks of 8
    if (chunk < 1176) {
      int r = chunk / 24, c8 = (chunk % 24) * 8;
      int tr = r / 7, tc = r % 7;
      int h = wh * 7 + tr + 3; if (h >= 56) h -= 56;
      int w = wwi * 7 + tc + 3; if (w >= 56) w -= 56;
      const float* p = x + (((size_t)b * 56 + h) * 56 + w) * 192 + c8;
      bf16x8 v;
#pragma unroll
      for (int j = 0; j < 8; ++j) v[j] = (bf)p[j];
      *(bf16x8*)(Xl + r * X_STRIDE + c8) = v;
    }
  }
  if (tid < 392) {  // 49 rows x 8 chunks of 8 cols
    int r = tid >> 3, c8 = (tid & 7) * 8;
    const float* p = tblg + r * 64 + c8;
    bf16x4 v0, v1;
#pragma unroll
    for (int j = 0; j < 4; ++j) { v0[j] = (bf)p[j]; v1[j] = (bf)p[4 + j]; }
    *(bf16x4*)(Tb + r * TB_STRIDE + c8) = v0;
    *(bf16x4*)(Tb + r * TB_STRIDE + c8 + 4) = v1;
  }
  __syncthreads();

  // ---- phase 1a: K,V columns. wave ncol: cols [192 + 96*ncol, +96), rows [32*mrow,+32) ----
  {
    f32x4 acc[2][6] = {};
#pragma unroll
    for (int ks = 0; ks < 6; ++ks) {
      bf16x8 a[2];
#pragma unroll
      for (int mt = 0; mt < 2; ++mt) {
        int t = mrow * 32 + mt * 16 + l15; if (t > 48) t = 48;  // dup row; masked later
        a[mt] = *(const bf16x8*)(Xl + t * X_STRIDE + ks * 32 + g * 8);
      }
#pragma unroll
      for (int nt = 0; nt < 6; ++nt) {
        int n = 192 + ncol * 96 + nt * 16 + l15;
        bf16x8 bfr = *(const bf16x8*)(wqkvT + (size_t)n * 192 + ks * 32 + g * 8);
#pragma unroll
        for (int mt = 0; mt < 2; ++mt) acc[mt][nt] = MFMA16(a[mt], bfr, acc[mt][nt]);
      }
    }
    // scatter K,V into R1/R2 (disjoint from X in R0 -> no barrier needed)
#pragma unroll
    for (int nt = 0; nt < 6; ++nt) {
      int n = 192 + ncol * 96 + nt * 16 + l15;
      int s3 = n / 192;               // 1 = K, 2 = V
      int lc = n - s3 * 192;
      int hd = lc >> 5, d = lc & 31;
#pragma unroll
      for (int mt = 0; mt < 2; ++mt) {
#pragma unroll
        for (int r = 0; r < 4; ++r) {
          int t = mrow * 32 + mt * 16 + 4 * g + r;
          bf bv = (bf)acc[mt][nt][r];
          if (s3 == 1) { if (t < 49) Kl[(hd * 49 + t) * QK_STRIDE + d] = bv; }
          else         { Vl[(hd * 32 + d) * VT_STRIDE + t] = bv; }  // t>=49 dup, killed by P==0
        }
      }
    }
  }

  // ---- phase 1b: Q columns. wave ncol: cols [48*ncol, +48) ----
  {
    f32x4 qacc[2][3] = {};
#pragma unroll
    for (int ks = 0; ks < 6; ++ks) {
      bf16x8 a[2];
#pragma unroll
      for (int mt = 0; mt < 2; ++mt) {
        int t = mrow * 32 + mt * 16 + l15; if (t > 48) t = 48;
        a[mt] = *(const bf16x8*)(Xl + t * X_STRIDE + ks * 32 + g * 8);
      }
#pragma unroll
      for (int nt = 0; nt < 3; ++nt) {
        int n = ncol * 48 + nt * 16 + l15;
        bf16x8 bfr = *(const bf16x8*)(wqkvT + (size_t)n * 192 + ks * 32 + g * 8);
#pragma unroll
        for (int mt = 0; mt < 2; ++mt) qacc[mt][nt] = MFMA16(a[mt], bfr, qacc[mt][nt]);
      }
    }
    __syncthreads();  // all X reads done; R0 becomes Q
#pragma unroll
    for (int nt = 0; nt < 3; ++nt) {
      int n = ncol * 48 + nt * 16 + l15;
      int hd = n >> 5, d = n & 31;
#pragma unroll
      for (int mt = 0; mt < 2; ++mt) {
#pragma unroll
        for (int r = 0; r < 4; ++r) {
          int t = mrow * 32 + mt * 16 + 4 * g + r;
          if (t < 49) Ql[(hd * 49 + t) * QK_STRIDE + d] = (bf)qacc[mt][nt][r];
        }
      }
    }
  }
  __syncthreads();

  // ---- phase 3a: S^T = K·Q^T (permuted tiles), bias, exp, lane-local softmax ----
  // 24 items = (head 0..5) x (q-tile 0..3); 3 per wave.
  unsigned pp[3][4][2];  // [item][T][half]: P[q=l15][kt = g*8 + 4*(T&1) + 32*(T>>1) + (0..3)]
#pragma unroll
  for (int ii = 0; ii < 3; ++ii) {
    int item = wave + ii * 8;
    int head = item >> 2, mq = item & 3;
    const bf* Qh = Ql + head * 49 * QK_STRIDE;
    const bf* Kh = Kl + head * 49 * QK_STRIDE;

    int q = mq * 16 + l15;
    int qc = q > 48 ? 48 : q;  // dup row; output rows q>=49 discarded
    bf16x8 qf = *(const bf16x8*)(Qh + qc * QK_STRIDE + g * 8);  // B-frag: Q[q][d]

    f32x4 sa[4];
#pragma unroll
    for (int T = 0; T < 4; ++T) {
      int kt = ((l15 >> 2) << 3) + ((T & 1) << 2) + ((T >> 1) << 5) + (l15 & 3);
      int ktc = kt > 48 ? 48 : kt;  // dup row; killed by NEG bias col
      bf16x8 kf = *(const bf16x8*)(Kh + ktc * QK_STRIDE + g * 8);  // A-frag: K[kt][d]
      f32x4 z = {};
      sa[T] = MFMA16(kf, qf, z);
    }

    // scale + bias + exp (no max-subtract: |logit| <~ 15, masked -> exp(-1e9)=0)
    float e[4][4];
    float lsum = 0.0f;
#pragma unroll
    for (int T = 0; T < 4; ++T) {
      int cb = (g << 3) + ((T & 1) << 2) + ((T >> 1) << 5);
      bf16x4 bias = *(const bf16x4*)(Tb + qc * TB_STRIDE + cb);
#pragma unroll
      for (int r = 0; r < 4; ++r) {
        float ev = __expf(sa[T][r] * kScale + (float)bias[r]);
        e[T][r] = ev;
        lsum += ev;
      }
    }
    lsum += __shfl_xor(lsum, 16);
    lsum += __shfl_xor(lsum, 32);
    float rinv = 1.0f / lsum;
#pragma unroll
    for (int T = 0; T < 4; ++T) {
      pp[ii][T][0] = pack2(e[T][0] * rinv, e[T][1] * rinv);
      pp[ii][T][1] = pack2(e[T][2] * rinv, e[T][3] * rinv);
    }
  }
  __syncthreads();  // K reads done; R1 -> O

  // ---- phase 3b: O = P·V, A-frags straight from pp registers ----
  for (int ii = 0; ii < 3; ++ii) {
    int item = wave + ii * 8;
    int head = item >> 2, mq = item & 3;
    const bf* Vh = Vl + head * 32 * VT_STRIDE;

    f32x4 o0 = {}, o1 = {};
#pragma unroll
    for (int ks = 0; ks < 2; ++ks) {
      union { unsigned u[4]; bf16x8 v; } af;
      af.u[0] = pp[ii][2 * ks][0];
      af.u[1] = pp[ii][2 * ks][1];
      af.u[2] = pp[ii][2 * ks + 1][0];
      af.u[3] = pp[ii][2 * ks + 1][1];
      bf16x8 v0 = *(const bf16x8*)(Vh + l15 * VT_STRIDE + ks * 32 + g * 8);
      bf16x8 v1 = *(const bf16x8*)(Vh + (16 + l15) * VT_STRIDE + ks * 32 + g * 8);
      o0 = MFMA16(af.v, v0, o0);
      o1 = MFMA16(af.v, v1, o1);
    }
#pragma unroll
    for (int r = 0; r < 4; ++r) {
      int orow = mq * 16 + 4 * g + r;
      if (orow < 49) {
        Ol[orow * O_STRIDE + head * 32 + l15]      = (bf)o0[r];
        Ol[orow * O_STRIDE + head * 32 + 16 + l15] = (bf)o1[r];
      }
    }
  }
  __syncthreads();

  // ---- phase 4: proj GEMM (49x192x192) + bias, inverse roll fused into stores ----
  f32x4 pacc[2][3] = {};
#pragma unroll
  for (int ks = 0; ks < 6; ++ks) {
    int t0 = mrow * 32 + l15;      if (t0 > 48) t0 = 48;
    int t1 = mrow * 32 + 16 + l15; if (t1 > 48) t1 = 48;
    bf16x8 a0 = *(const bf16x8*)(Ol + t0 * O_STRIDE + ks * 32 + g * 8);
    bf16x8 a1 = *(const bf16x8*)(Ol + t1 * O_STRIDE + ks * 32 + g * 8);
#pragma unroll
    for (int nt = 0; nt < 3; ++nt) {
      bf16x8 bfr = *(const bf16x8*)(woutT + (size_t)(ncol * 48 + nt * 16 + l15) * 192 + ks * 32 + g * 8);
      pacc[0][nt] = MFMA16(a0, bfr, pacc[0][nt]);
      pacc[1][nt] = MFMA16(a1, bfr, pacc[1][nt]);
    }
  }
#pragma unroll
  for (int nt = 0; nt < 3; ++nt) {
    int col = ncol * 48 + nt * 16 + l15;
    float bo = bout[col];
#pragma unroll
    for (int mt = 0; mt < 2; ++mt) {
#pragma unroll
      for (int r = 0; r < 4; ++r) {
        int t = mrow * 32 + mt * 16 + 4 * g + r;
        if (t < 49) {
          int tr = t / 7, tc = t % 7;
          int h = wh * 7 + tr + 3; if (h >= 56) h -= 56;
          int w2 = wwi * 7 + tc + 3; if (w2 >= 56) w2 -= 56;
          out[(((size_t)b * 56 + h) * 56 + w2) * 192 + col] = pacc[mt][nt][r] + bo;
        }
      }
    }
  }
}

extern "C" void kernel_launch(void* const* d_in, const int* in_sizes, int n_in,
                              void* d_out, int out_size, void* d_ws, size_t ws_size,
                              hipStream_t stream) {
  const float* x = (const float*)d_in[0];
  const float* wqkv = (const float*)d_in[1];
  const float* wout = (const float*)d_in[2];
  const float* bout = (const float*)d_in[3];
  const float* pos = (const float*)d_in[4];
  char* ws = (char*)d_ws;

  hipLaunchKernelGGL(prep_kernel, dim3(128), dim3(256), 0, stream, wqkv, wout, pos, ws);
  hipLaunchKernelGGL(fused_kernel, dim3(2048), dim3(512), 0, stream,
                     x, bout, (const char*)ws, (float*)d_out);
}